// Round 1
// baseline (35291.168 us; speedup 1.0000x reference)
//
#include <hip/hip_runtime.h>
#include <cstdint>

#define BLK 512
#define RROWS 16
#define TSTEPS 32

// ws layout (float offsets)
#define OFF_PCAT   0          // [8192][600]
#define OFF_WSUMT  4915200    // [784][600]  (W1+W2)^T for mu|lv
#define OFF_W2T    5385600    // [784][600]  W2^T (x_hat part) mu|lv
#define OFF_W3T    5856000    // [100][600]  h_dec enc part^T mu|lv
#define OFF_WHHT   5916000    // [100][600]  Whh^T mu|lv
#define OFF_WDECT  5976000    // [100][600]  Wih_dec^T | Whh_dec^T
#define OFF_WHEADT 6036000    // [100][200]  Wmu^T | Wlv^T
#define OFF_WWT    6056000    // [100][784]  Wwrite^T
#define OFF_BIHC   6134400    // [600] bih mu|lv
#define OFF_BHHC   6135000    // [600] bhh mu|lv

__device__ __forceinline__ float sigf(float x){ return 1.0f/(1.0f+__expf(-x)); }
__device__ __forceinline__ float tanhfast(float x){ return 1.0f - 2.0f/(__expf(2.0f*x)+1.0f); }
__device__ __forceinline__ float bf2f(unsigned short u){ return __uint_as_float(((unsigned int)u)<<16); }
__device__ __forceinline__ unsigned short f2bf(float f){ unsigned int x = __float_as_uint(f); return (unsigned short)((x + 0x8000u) >> 16); }
__device__ __forceinline__ void fma4(float4& a, float s, const float4 w){
  a.x = fmaf(s, w.x, a.x); a.y = fmaf(s, w.y, a.y);
  a.z = fmaf(s, w.z, a.z); a.w = fmaf(s, w.w, a.w);
}

// ---------- one-time weight re-layout (runs every launch; stream-ordered) ----------
__global__ void init_weights(const float* ih_mu, const float* whh_mu, const float* bih_mu, const float* bhh_mu,
                             const float* ih_lv, const float* whh_lv, const float* bih_lv, const float* bhh_lv,
                             const float* wmu, const float* wlv,
                             const float* wih_dec, const float* whh_dec,
                             const float* wwrite, float* ws)
{
  int u = blockIdx.x*256 + threadIdx.x;
  const int ENC = 1668;
  float v; int dst;
  if (u < 470400) { int k = u/600, j = u%600; dst = OFF_WSUMT + u;
    v = (j<300) ? ih_mu[j*ENC+k]+ih_mu[j*ENC+784+k]
                : ih_lv[(j-300)*ENC+k]+ih_lv[(j-300)*ENC+784+k]; }
  else if ((u-=470400) < 470400) { int k=u/600, j=u%600; dst = OFF_W2T+u;
    v = (j<300)? ih_mu[j*ENC+784+k] : ih_lv[(j-300)*ENC+784+k]; }
  else if ((u-=470400) < 60000) { int k=u/600, j=u%600; dst = OFF_W3T+u;
    v = (j<300)? ih_mu[j*ENC+1568+k] : ih_lv[(j-300)*ENC+1568+k]; }
  else if ((u-=60000) < 60000) { int k=u/600, j=u%600; dst=OFF_WHHT+u;
    v = (j<300)? whh_mu[j*100+k] : whh_lv[(j-300)*100+k]; }
  else if ((u-=60000) < 60000) { int k=u/600, j=u%600; dst=OFF_WDECT+u;
    v = (j<300)? wih_dec[j*100+k] : whh_dec[(j-300)*100+k]; }
  else if ((u-=60000) < 20000) { int k=u/200, i=u%200; dst=OFF_WHEADT+u;
    v = (i<100)? wmu[i*100+k] : wlv[(i-100)*100+k]; }
  else if ((u-=20000) < 78400) { int i=u/784, k=u%784; dst=OFF_WWT+u;
    v = wwrite[k*100+i]; }
  else if ((u-=78400) < 600) { dst=OFF_BIHC+u; v = (u<300)? bih_mu[u] : bih_lv[u-300]; }
  else if ((u-=600) < 600) { dst=OFF_BHHC+u; v = (u<300)? bhh_mu[u] : bhh_lv[u-300]; }
  else return;
  ws[dst] = v;
}

// P = x @ (W1+W2)^T + bih  (mu | lv concatenated, [8192][600])
__global__ void init_pcat(const float* __restrict__ x, float* __restrict__ ws)
{
  int u = blockIdx.x*256+threadIdx.x;           // (b, jq) quads: 8192*150
  if (u >= 8192*150) return;
  int b = u/150, jq = u%150;
  const float4* wsum4 = (const float4*)(ws + OFF_WSUMT);
  float4 acc = ((const float4*)(ws + OFF_BIHC))[jq];
  const float* xb = x + b*784;
  #pragma unroll 8
  for (int k = 0; k < 784; ++k) {
    float xv = xb[k];
    fma4(acc, xv, wsum4[k*150 + jq]);
  }
  ((float4*)(ws + OFF_PCAT))[u] = acc;
}

// ---------- persistent main kernel: 16 rows per block, full 32-step scan ----------
__global__ __launch_bounds__(BLK, 4) void draw_main(
    const float* __restrict__ noise,
    const float* __restrict__ bih_dec, const float* __restrict__ bhh_dec,
    const float* __restrict__ bmu, const float* __restrict__ blv,
    const float* __restrict__ bwrite,
    const float* __restrict__ ws, float* __restrict__ out)
{
  extern __shared__ char smem[];
  unsigned short* s_bf = (unsigned short*)smem;     // [16][784] bf16 sigmoid(c)
  float* gates = (float*)(smem + 25088);            // [16][300] (r,z summed; n = i_n)
  float* ghn   = (float*)(smem + 44288);            // [16][100] h-side n gate
  float* hst   = (float*)(smem + 50688);            // [3][16][100]: mu, lv, dec
  float* zbuf  = (float*)(smem + 69888);            // [16][100]

  const int tid = threadIdx.x;
  const int r0 = blockIdx.x * RROWS;

  const float4* W2T4   = (const float4*)(ws + OFF_W2T);
  const float4* W3T4   = (const float4*)(ws + OFF_W3T);
  const float4* WHHT4  = (const float4*)(ws + OFF_WHHT);
  const float4* WDECT4 = (const float4*)(ws + OFF_WDECT);
  const float*  WHEADT = ws + OFF_WHEADT;
  const float4* WWT4   = (const float4*)(ws + OFF_WWT);
  const float4* PCAT4  = (const float4*)(ws + OFF_PCAT);
  const float4* BHHC4  = (const float4*)(ws + OFF_BHHC);
  const float4* bih_dec4 = (const float4*)bih_dec;
  const float4* bhh_dec4 = (const float4*)bhh_dec;
  const float4* bwrite4  = (const float4*)bwrite;

  float* out_c  = out;
  float* out_mu = out + 8192*784;
  float* out_lv = out_mu + TSTEPS*8192*100;

  // t=0 state: h=0, c=0 -> sigmoid(c)=0.5
  for (int i = tid; i < RROWS*100*3; i += BLK) hst[i] = 0.0f;
  for (int i = tid; i < RROWS*784; i += BLK) s_bf[i] = 0x3F00;   // bf16(0.5)
  float4 creg[7];
  #pragma unroll
  for (int q = 0; q < 7; ++q) creg[q] = make_float4(0.f,0.f,0.f,0.f);
  __syncthreads();

  for (int t = 0; t < TSTEPS; ++t) {
    // ---- encoder GRUs (g=0: mu, g=1: lv) ----
    for (int g = 0; g < 2; ++g) {
      float* hM = hst + g*1600;
      // gates: gi = P - s@W2^T + h_dec@W3^T ; gh = bhh + h@Whh^T
      for (int u = tid; u < RROWS*75; u += BLK) {
        int r = u/75, jq = u%75;
        int cq = g*75 + jq;
        float4 ai = PCAT4[(r0+r)*150 + cq];
        const unsigned short* srow = s_bf + r*784;
        const float4* wp = W2T4 + cq;
        #pragma unroll 8
        for (int k = 0; k < 784; ++k) {
          float sv = bf2f(srow[k]);
          fma4(ai, -sv, wp[k*150]);
        }
        const float* hd = hst + 3200 + r*100;
        const float4* w3p = W3T4 + cq;
        #pragma unroll 4
        for (int k = 0; k < 100; ++k) fma4(ai, hd[k], w3p[k*150]);
        float4 ah = BHHC4[cq];
        const float* hm = hM + r*100;
        const float4* whp = WHHT4 + cq;
        #pragma unroll 4
        for (int k = 0; k < 100; ++k) fma4(ah, hm[k], whp[k*150]);
        int j0 = jq*4;
        if (j0 < 200) {            // r,z gates: store i+h sum
          float4 gs; gs.x=ai.x+ah.x; gs.y=ai.y+ah.y; gs.z=ai.z+ah.z; gs.w=ai.w+ah.w;
          ((float4*)(gates + r*300))[jq] = gs;
        } else {                   // n gate: keep i and h separate
          ((float4*)(gates + r*300))[jq] = ai;
          ((float4*)(ghn + r*100))[jq - 50] = ah;
        }
      }
      __syncthreads();
      // GRU update
      for (int u = tid; u < RROWS*100; u += BLK) {
        int r = u/100, i = u%100;
        float rg = sigf(gates[r*300+i]);
        float zg = sigf(gates[r*300+100+i]);
        float nn = tanhfast(fmaf(rg, ghn[r*100+i], gates[r*300+200+i]));
        float h = hM[u];
        hM[u] = (1.0f - zg)*nn + zg*h;
      }
      __syncthreads();
    }
    // ---- heads + reparameterize ----
    for (int u = tid; u < RROWS*100; u += BLK) {
      int r = u/100, i = u%100;
      float macc = bmu[i], lacc = blv[i];
      const float* hm = hst + r*100;
      const float* hl = hst + 1600 + r*100;
      const float* wh = WHEADT + i;
      #pragma unroll 4
      for (int k = 0; k < 100; ++k) {
        macc = fmaf(hm[k], wh[k*200], macc);
        lacc = fmaf(hl[k], wh[k*200+100], lacc);
      }
      macc = fmaxf(macc, 0.0f); lacc = fmaxf(lacc, 0.0f);
      int oidx = t*819200 + (r0 + r)*100 + i;   // noise shares this layout
      out_mu[oidx] = macc;
      out_lv[oidx] = lacc;
      zbuf[u] = fmaf(noise[oidx], __expf(0.5f*lacc), macc);
    }
    __syncthreads();
    // ---- decoder GRU gates ----
    for (int u = tid; u < RROWS*75; u += BLK) {
      int r = u/75, jq = u%75;
      float4 ai = bih_dec4[jq];
      const float* zr = zbuf + r*100;
      const float4* wip = WDECT4 + jq;
      #pragma unroll 4
      for (int k = 0; k < 100; ++k) fma4(ai, zr[k], wip[k*150]);
      float4 ah = bhh_dec4[jq];
      const float* hd = hst + 3200 + r*100;
      const float4* whp = WDECT4 + 75 + jq;
      #pragma unroll 4
      for (int k = 0; k < 100; ++k) fma4(ah, hd[k], whp[k*150]);
      int j0 = jq*4;
      if (j0 < 200) {
        float4 gs; gs.x=ai.x+ah.x; gs.y=ai.y+ah.y; gs.z=ai.z+ah.z; gs.w=ai.w+ah.w;
        ((float4*)(gates + r*300))[jq] = gs;
      } else {
        ((float4*)(gates + r*300))[jq] = ai;
        ((float4*)(ghn + r*100))[jq - 50] = ah;
      }
    }
    __syncthreads();
    // ---- decoder GRU update ----
    for (int u = tid; u < RROWS*100; u += BLK) {
      int r = u/100, i = u%100;
      float rg = sigf(gates[r*300+i]);
      float zg = sigf(gates[r*300+100+i]);
      float nn = tanhfast(fmaf(rg, ghn[r*100+i], gates[r*300+200+i]));
      float h = hst[3200 + u];
      hst[3200 + u] = (1.0f - zg)*nn + zg*h;
    }
    __syncthreads();
    // ---- canvas write: c += h_dec@Ww^T + bwrite; emit next-step sigmoid(c) ----
    #pragma unroll
    for (int q = 0; q < 7; ++q) {
      int u = tid + q*BLK;
      if (u < RROWS*196) {
        int r = u/196, kq = u%196;
        float4 acc = bwrite4[kq];
        const float* hd = hst + 3200 + r*100;
        const float4* wp = WWT4 + kq;
        #pragma unroll 4
        for (int i = 0; i < 100; ++i) fma4(acc, hd[i], wp[i*196]);
        creg[q].x += acc.x; creg[q].y += acc.y; creg[q].z += acc.z; creg[q].w += acc.w;
        float4 sg; sg.x = sigf(creg[q].x); sg.y = sigf(creg[q].y);
        sg.z = sigf(creg[q].z); sg.w = sigf(creg[q].w);
        if (t < TSTEPS-1) {
          unsigned short* sp = s_bf + r*784 + kq*4;
          sp[0]=f2bf(sg.x); sp[1]=f2bf(sg.y); sp[2]=f2bf(sg.z); sp[3]=f2bf(sg.w);
        } else {
          ((float4*)out_c)[(r0+r)*196 + kq] = sg;
        }
      }
    }
    __syncthreads();
  }
}

extern "C" void kernel_launch(void* const* d_in, const int* in_sizes, int n_in,
                              void* d_out, int out_size, void* d_ws, size_t ws_size,
                              hipStream_t stream) {
  (void)in_sizes; (void)n_in; (void)out_size; (void)ws_size;
  const float* x      = (const float*)d_in[0];
  const float* noise  = (const float*)d_in[1];
  const float* ih_mu  = (const float*)d_in[2];
  const float* whh_mu = (const float*)d_in[3];
  const float* bih_mu = (const float*)d_in[4];
  const float* bhh_mu = (const float*)d_in[5];
  const float* ih_lv  = (const float*)d_in[6];
  const float* whh_lv = (const float*)d_in[7];
  const float* bih_lv = (const float*)d_in[8];
  const float* bhh_lv = (const float*)d_in[9];
  const float* wmu    = (const float*)d_in[10];
  const float* bmu    = (const float*)d_in[11];
  const float* wlv    = (const float*)d_in[12];
  const float* blv    = (const float*)d_in[13];
  const float* wih_dec= (const float*)d_in[14];
  const float* whh_dec= (const float*)d_in[15];
  const float* bih_dec= (const float*)d_in[16];
  const float* bhh_dec= (const float*)d_in[17];
  const float* wwrite = (const float*)d_in[18];
  const float* bwrite = (const float*)d_in[19];
  float* ws  = (float*)d_ws;
  float* out = (float*)d_out;

  hipFuncSetAttribute(reinterpret_cast<const void*>(draw_main),
                      hipFuncAttributeMaxDynamicSharedMemorySize, 76288);

  init_weights<<<4768, 256, 0, stream>>>(ih_mu, whh_mu, bih_mu, bhh_mu,
                                         ih_lv, whh_lv, bih_lv, bhh_lv,
                                         wmu, wlv, wih_dec, whh_dec, wwrite, ws);
  init_pcat<<<4800, 256, 0, stream>>>(x, ws);
  draw_main<<<512, BLK, 76288, stream>>>(noise, bih_dec, bhh_dec,
                                         bmu, blv, bwrite, ws, out);
}

// Round 2
// 7498.642 us; speedup vs baseline: 4.7063x; 4.7063x over previous
//
#include <hip/hip_runtime.h>
#include <cstdint>

typedef short bf16x8 __attribute__((ext_vector_type(8)));
typedef float f32x4 __attribute__((ext_vector_type(4)));

#define MFMA(a,b,c) __builtin_amdgcn_mfma_f32_16x16x32_bf16((a),(b),(c),0,0,0)

// ---------------- ws layout (bytes) ----------------
constexpr int FR = 512;                          // bf16 elems per fragment (64 lanes x 8)
constexpr size_t OP2   = 0;                                  // P2 bf16 [512rt][42nt][64][4]
constexpr size_t SZP2  = (size_t)512*42*256*2;               // 11,010,048
constexpr size_t OWSUM = OP2 + SZP2;                         // [25ks][42nt][512] bf16
constexpr size_t SZWSUM= (size_t)25*42*FR*2;
constexpr size_t OWEAM = OWSUM + SZWSUM;                     // enc A-side weights mu [28][21][512]
constexpr size_t SZWEA = (size_t)28*21*FR*2;
constexpr size_t OWEAL = OWEAM + SZWEA;
constexpr size_t OWEBM = OWEAL + SZWEA;                      // enc h-side [4][21][512]
constexpr size_t SZWEB = (size_t)4*21*FR*2;
constexpr size_t OWEBL = OWEBM + SZWEB;
constexpr size_t OWH   = OWEBL + SZWEB;                      // heads [8][14][512]
constexpr size_t SZWH  = (size_t)8*14*FR*2;
constexpr size_t OWD   = OWH + SZWH;                         // dec [8][21][512]
constexpr size_t SZWD  = (size_t)8*21*FR*2;
constexpr size_t OWW   = OWD + SZWD;                         // write [4][49][512]
constexpr size_t SZWW  = (size_t)4*49*FR*2;
constexpr size_t OBP2  = OWW + SZWW;                         // f32 bias frags
constexpr size_t OBGHN = OBP2 + (size_t)42*256*4;
constexpr size_t OBDI  = OBGHN + (size_t)2*7*256*4;
constexpr size_t OBDHN = OBDI + (size_t)21*256*4;
constexpr size_t OBWR  = OBDHN + (size_t)7*256*4;
constexpr size_t OBH   = OBWR + (size_t)49*256*4;            // end ~14.1 MB

__device__ __forceinline__ float sigf(float x){ return 1.0f/(1.0f+__expf(-x)); }
__device__ __forceinline__ float tanhfast(float x){ return 1.0f - 2.0f/(__expf(2.0f*x)+1.0f); }
__device__ __forceinline__ float bf2f(unsigned short u){ return __uint_as_float(((unsigned int)u)<<16); }
__device__ __forceinline__ unsigned short f2bf(float f){ unsigned int x = __float_as_uint(f); return (unsigned short)((x + 0x8000u) >> 16); }

// ---------------- weight / bias fragment packing ----------------
__global__ void init_pack(
    const float* __restrict__ ihmu, const float* __restrict__ whhmu,
    const float* __restrict__ bihmu, const float* __restrict__ bhhmu,
    const float* __restrict__ ihlv, const float* __restrict__ whhlv,
    const float* __restrict__ bihlv, const float* __restrict__ bhhlv,
    const float* __restrict__ wmu, const float* __restrict__ bmu,
    const float* __restrict__ wlv, const float* __restrict__ blv,
    const float* __restrict__ ihd, const float* __restrict__ whhd,
    const float* __restrict__ bihd, const float* __restrict__ bhhd,
    const float* __restrict__ wwr, const float* __restrict__ bwr,
    char* __restrict__ wsb)
{
  int u = blockIdx.x*256 + threadIdx.x;
  if (u < 1469440) {
    int v = u; size_t off; int NT; int region;
    if      (v < 537600)            { region=0; off=OWSUM; NT=42; }
    else if ((v-=537600) < 301056)  { region=1; off=OWEAM; NT=21; }
    else if ((v-=301056) < 301056)  { region=2; off=OWEAL; NT=21; }
    else if ((v-=301056) < 43008)   { region=3; off=OWEBM; NT=21; }
    else if ((v-=43008)  < 43008)   { region=4; off=OWEBL; NT=21; }
    else if ((v-=43008)  < 57344)   { region=5; off=OWH;   NT=14; }
    else if ((v-=57344)  < 86016)   { region=6; off=OWD;   NT=21; }
    else    { v-=86016;   region=7; off=OWW;   NT=49; }
    int ks = v / (NT*512); int rem = v - ks*(NT*512);
    int nt = rem >> 9; int li = rem & 511;
    int l = li >> 3, e = li & 7;
    int k = ks*32 + ((l>>4)<<3) + e;
    int c = l & 15;
    float val = 0.f;
    if (region==0) {
      int gru = nt/21, ntg = nt%21, gate = ntg/7, j = (ntg%7)*16 + c;
      if (j<100 && k<784) { const float* IH = gru? ihlv : ihmu; int jj = gate*100+j;
        val = IH[(size_t)jj*1668 + k] + IH[(size_t)jj*1668 + 784 + k]; }
    } else if (region==1 || region==2) {
      const float* IH = (region==2)? ihlv : ihmu;
      int gate = nt/7, j = (nt%7)*16 + c;
      if (j<100) { int jj = gate*100+j;
        if (k<784)      val = -IH[(size_t)jj*1668 + 784 + k];
        else if (k<884) val =  IH[(size_t)jj*1668 + 1568 + (k-784)]; }
    } else if (region==3 || region==4) {
      const float* WHH = (region==4)? whhlv : whhmu;
      int gate = nt/7, j = (nt%7)*16 + c;
      if (j<100 && k<100) val = WHH[(gate*100+j)*100 + k];
    } else if (region==5) {
      int grp = nt/7, j = (nt%7)*16 + c;
      if (j<100) {
        if (grp==0) { if (k<100) val = wmu[j*100+k]; }
        else        { if (k>=128 && k<228) val = wlv[j*100 + (k-128)]; }
      }
    } else if (region==6) {
      int gate = nt/7, j = (nt%7)*16 + c;
      if (j<100) { int jj = gate*100+j;
        if (k<100)               val = ihd[jj*100+k];
        else if (k>=128 && k<228) val = whhd[jj*100 + (k-128)]; }
    } else {
      int n = nt*16 + c;
      if (k<100) val = wwr[n*100+k];
    }
    *(unsigned short*)(wsb + off + (size_t)v*2) = f2bf(val);
    return;
  }
  u -= 1469440;
  if (u >= 37632) return;
  float val = 0.f; size_t off; int v = u;
  if (v < 10752) { off = OBP2;
    int nt = v>>8, li = v&255, l = li>>2, c = l&15;
    int gru = nt/21, ntg = nt%21, gate = ntg/7, j = (ntg%7)*16 + c;
    if (j<100) {
      const float* BI = gru? bihlv : bihmu; const float* BH = gru? bhhlv : bhhmu;
      val = BI[gate*100+j] + ((gate<2)? BH[gate*100+j] : 0.f);
    }
  } else if ((v-=10752) < 3584) { off = OBGHN;
    int g = v/1792, r2 = v - g*1792, p = r2>>8, li = r2&255, l = li>>2, c = l&15;
    int j = p*16+c;
    if (j<100) val = (g? bhhlv : bhhmu)[200+j];
  } else if ((v-=3584) < 5376) { off = OBDI;
    int nt = v>>8, li = v&255, l = li>>2, c = l&15;
    int gate = nt/7, j = (nt%7)*16+c;
    if (j<100) val = (gate<2)? (bihd[gate*100+j]+bhhd[gate*100+j]) : bihd[200+j];
  } else if ((v-=5376) < 1792) { off = OBDHN;
    int p = v>>8, li = v&255, l = li>>2, c = l&15; int j = p*16+c;
    if (j<100) val = bhhd[200+j];
  } else if ((v-=1792) < 12544) { off = OBWR;
    int nt = v>>8, li = v&255, l = li>>2, c = l&15;
    val = bwr[nt*16+c];
  } else { v -= 12544; off = OBH;
    int nt = v>>8, li = v&255, l = li>>2, c = l&15;
    int grp = nt/7, j = (nt%7)*16+c;
    if (j<100) val = grp? blv[j] : bmu[j];
  }
  *(float*)(wsb + off + (size_t)v*4) = val;
}

// ---------------- P2 = x@(W1+W2)^T + bias, fragment-packed bf16 ----------------
__global__ __launch_bounds__(512) void init_p2(const float* __restrict__ x, char* __restrict__ wsb)
{
  __shared__ char xt[16*1600];
  const int tid = threadIdx.x, l = tid&63, w = tid>>6;
  const int lr = l&15, lg = l>>4;
  const int rt = blockIdx.x;
  for (int i = tid; i < 16*800; i += 512) {
    int row = i/800, col = i - row*800;
    unsigned short hv = 0;
    if (col < 784) hv = f2bf(x[(size_t)(rt*16+row)*784 + col]);
    *(unsigned short*)(xt + ((row*1600 + col*2) ^ ((row&7)<<4))) = hv;
  }
  __syncthreads();
  const char* WS = wsb + OWSUM;
  for (int nt = w; nt < 42; nt += 8) {
    f32x4 acc = *(const f32x4*)(wsb + OBP2 + (size_t)(nt*256 + l*4)*4);
    const char* wp = WS + (size_t)(nt*512 + l*8)*2;
    #pragma unroll 5
    for (int ks = 0; ks < 25; ++ks) {
      bf16x8 a = *(const bf16x8*)(xt + ((lr*1600 + ks*64 + lg*16) ^ ((lr&7)<<4)));
      bf16x8 b = *(const bf16x8*)(wp + (size_t)ks*42*512*2);
      acc = MFMA(a,b,acc);
    }
    ushort4 ov; ov.x=f2bf(acc[0]); ov.y=f2bf(acc[1]); ov.z=f2bf(acc[2]); ov.w=f2bf(acc[3]);
    *(ushort4*)(wsb + OP2 + ((size_t)(rt*42+nt)*64 + l)*8) = ov;
  }
}

// ---------------- encoder GRU (GEMM + in-register update) ----------------
__device__ __forceinline__ void enc_gru(
    int g, int wbase, const char* wsb, char* Aenc, char* Ahml,
    int blk, int l, int lr, int lg, f32x4 (&h)[2])
{
  const char* WA = wsb + (g? OWEAL : OWEAM);
  const char* WB = wsb + (g? OWEBL : OWEBM);
  f32x4 ar[2], az[2], an[2], ahn[2];
  #pragma unroll
  for (int rep=0; rep<2; ++rep) {
    int tj = wbase + rep*8;
    if (tj < 14) {
      int mt = tj/7, p = tj - mt*7;
      size_t pb = OP2 + (((size_t)(blk*2+mt)*42 + g*21 + p)*64 + l)*8;
      ushort4 pr = *(const ushort4*)(wsb + pb);
      ushort4 pz = *(const ushort4*)(wsb + pb + (size_t)7*64*8);
      ushort4 pn = *(const ushort4*)(wsb + pb + (size_t)14*64*8);
      ar[rep][0]=bf2f(pr.x); ar[rep][1]=bf2f(pr.y); ar[rep][2]=bf2f(pr.z); ar[rep][3]=bf2f(pr.w);
      az[rep][0]=bf2f(pz.x); az[rep][1]=bf2f(pz.y); az[rep][2]=bf2f(pz.z); az[rep][3]=bf2f(pz.w);
      an[rep][0]=bf2f(pn.x); an[rep][1]=bf2f(pn.y); an[rep][2]=bf2f(pn.z); an[rep][3]=bf2f(pn.w);
      ahn[rep] = *(const f32x4*)(wsb + OBGHN + (size_t)((g*7+p)*256 + l*4)*4);
      const char* wr = WA + (size_t)(p*512 + l*8)*2;
      const char* wz = WA + (size_t)((p+7)*512 + l*8)*2;
      const char* wn = WA + (size_t)((p+14)*512 + l*8)*2;
      int row = mt*16 + lr;
      int abase = row*1792 + lg*16;
      int axor = (row&7)<<4;
      #pragma unroll 2
      for (int ks=0; ks<28; ++ks) {
        bf16x8 a = *(const bf16x8*)(Aenc + ((abase + ks*64) ^ axor));
        size_t so = (size_t)ks*21*512*2;
        ar[rep] = MFMA(a, *(const bf16x8*)(wr+so), ar[rep]);
        az[rep] = MFMA(a, *(const bf16x8*)(wz+so), az[rep]);
        an[rep] = MFMA(a, *(const bf16x8*)(wn+so), an[rep]);
      }
      const char* vr = WB + (size_t)(p*512 + l*8)*2;
      const char* vz = WB + (size_t)((p+7)*512 + l*8)*2;
      const char* vn = WB + (size_t)((p+14)*512 + l*8)*2;
      int hbase = row*512 + g*256 + lg*16;
      #pragma unroll
      for (int ks=0; ks<4; ++ks) {
        bf16x8 a = *(const bf16x8*)(Ahml + ((hbase + ks*64) ^ axor));
        size_t so = (size_t)ks*21*512*2;
        ar[rep]  = MFMA(a, *(const bf16x8*)(vr+so), ar[rep]);
        az[rep]  = MFMA(a, *(const bf16x8*)(vz+so), az[rep]);
        ahn[rep] = MFMA(a, *(const bf16x8*)(vn+so), ahn[rep]);
      }
    }
  }
  __syncthreads();
  #pragma unroll
  for (int rep=0; rep<2; ++rep) {
    int tj = wbase + rep*8;
    if (tj < 14) {
      int mt = tj/7, p = tj - mt*7;
      int col = p*16 + lr;
      #pragma unroll
      for (int e=0;e<4;++e) {
        float rg = sigf(ar[rep][e]);
        float zg = sigf(az[rep][e]);
        float nn = tanhfast(fmaf(rg, ahn[rep][e], an[rep][e]));
        float hnew = nn + zg*(h[rep][e] - nn);
        h[rep][e] = hnew;
        if (col < 100) {
          int row = mt*16 + lg*4 + e;
          *(unsigned short*)(Ahml + ((row*512 + (g*128+col)*2) ^ ((row&7)<<4))) = f2bf(hnew);
        }
      }
    }
  }
}

// ---------------- main persistent kernel ----------------
__global__ __launch_bounds__(512,1) void draw_main(
    const float* __restrict__ noise, const char* __restrict__ wsb, float* __restrict__ out)
{
  extern __shared__ char sm[];
  char* Aenc = sm;              // [32][1792 B] bf16: sigc(784) | hdec(100) | pad
  char* Ahml = sm + 57344;      // [32][512 B]  bf16: hmu(100) pad | hlv(100) pad
  char* Adec = sm + 73728;      // [32][512 B]  bf16: z(100) pad | hdec(100) pad

  const int tid = threadIdx.x, l = tid&63, w = tid>>6;
  const int lr = l&15, lg = l>>4;
  const int blk = blockIdx.x;

  float* out_c  = out;
  float* out_mu = out + (size_t)8192*784;
  float* out_lv = out_mu + (size_t)32*8192*100;

  for (int i = tid; i < 32*896; i += 512) {
    int row = i/896, col = i - row*896;
    unsigned short v = (col<784)? (unsigned short)0x3F00 : (unsigned short)0;
    *(unsigned short*)(Aenc + ((row*1792 + col*2) ^ ((row&7)<<4))) = v;
  }
  for (int i = tid; i < 32*256; i += 512) {
    int row = i>>8, col = i&255;
    int a = (row*512 + col*2) ^ ((row&7)<<4);
    *(unsigned short*)(Ahml + a) = 0;
    *(unsigned short*)(Adec + a) = 0;
  }
  const f32x4 z4 = {0.f,0.f,0.f,0.f};
  f32x4 creg[13];
  #pragma unroll
  for (int q=0;q<13;++q) creg[q] = z4;
  f32x4 hm[2], hl[2], hd[2];
  #pragma unroll
  for (int q=0;q<2;++q){ hm[q]=z4; hl[q]=z4; hd[q]=z4; }
  __syncthreads();

  for (int t = 0; t < 32; ++t) {
    // ---- encoder GRUs ----
    enc_gru(0, w,        wsb, Aenc, Ahml, blk, l, lr, lg, hm);
    enc_gru(1, (w+2)&7,  wsb, Aenc, Ahml, blk, l, lr, lg, hl);
    __syncthreads();                       // A_hml complete for heads

    // ---- heads + reparameterize ----
    {
      const char* WH = wsb + OWH;
      f32x4 am[2], al[2];
      #pragma unroll
      for (int rep=0; rep<2; ++rep) {
        int j = w + rep*8;
        if (j < 14) {
          int mt = j/7, p = j - mt*7;
          am[rep] = *(const f32x4*)(wsb + OBH + (size_t)(p*256 + l*4)*4);
          al[rep] = *(const f32x4*)(wsb + OBH + (size_t)((7+p)*256 + l*4)*4);
          int row = mt*16 + lr;
          int hbase = row*512 + lg*16;
          int axor = (row&7)<<4;
          #pragma unroll
          for (int ks=0; ks<4; ++ks) {
            bf16x8 a0 = *(const bf16x8*)(Ahml + ((hbase + ks*64) ^ axor));
            bf16x8 a1 = *(const bf16x8*)(Ahml + ((hbase + 256 + ks*64) ^ axor));
            am[rep] = MFMA(a0, *(const bf16x8*)(WH + ((size_t)(ks*14+p)*512 + l*8)*2), am[rep]);
            al[rep] = MFMA(a1, *(const bf16x8*)(WH + ((size_t)((ks+4)*14+7+p)*512 + l*8)*2), al[rep]);
          }
        }
      }
      #pragma unroll
      for (int rep=0; rep<2; ++rep) {
        int j = w + rep*8;
        if (j < 14) {
          int mt = j/7, p = j - mt*7;
          int col = p*16 + lr;
          if (col < 100) {
            #pragma unroll
            for (int e=0;e<4;++e) {
              int row = mt*16 + lg*4 + e;
              float m  = fmaxf(am[rep][e], 0.f);
              float lv = fmaxf(al[rep][e], 0.f);
              size_t oidx = (size_t)t*819200 + (size_t)(blk*32+row)*100 + col;
              out_mu[oidx] = m;
              out_lv[oidx] = lv;
              float zz = fmaf(noise[oidx], __expf(0.5f*lv), m);
              *(unsigned short*)(Adec + ((row*512 + col*2) ^ ((row&7)<<4))) = f2bf(zz);
            }
          }
        }
      }
    }
    __syncthreads();                       // A_dec z-region ready

    // ---- decoder GRU ----
    {
      const char* WD = wsb + OWD;
      int wbase = (w+4)&7;
      f32x4 dr[2], dz[2], dn[2], dhn[2];
      #pragma unroll
      for (int rep=0; rep<2; ++rep) {
        int tj = wbase + rep*8;
        if (tj < 14) {
          int mt = tj/7, p = tj - mt*7;
          dr[rep]  = *(const f32x4*)(wsb + OBDI  + (size_t)(p*256 + l*4)*4);
          dz[rep]  = *(const f32x4*)(wsb + OBDI  + (size_t)((p+7)*256 + l*4)*4);
          dn[rep]  = *(const f32x4*)(wsb + OBDI  + (size_t)((p+14)*256 + l*4)*4);
          dhn[rep] = *(const f32x4*)(wsb + OBDHN + (size_t)(p*256 + l*4)*4);
          const char* br = WD + (size_t)(p*512 + l*8)*2;
          const char* bz = WD + (size_t)((p+7)*512 + l*8)*2;
          const char* bn = WD + (size_t)((p+14)*512 + l*8)*2;
          int row = mt*16 + lr;
          int abase = row*512 + lg*16;
          int axor = (row&7)<<4;
          #pragma unroll
          for (int ks=0; ks<8; ++ks) {
            bf16x8 a = *(const bf16x8*)(Adec + ((abase + ks*64) ^ axor));
            size_t so = (size_t)ks*21*512*2;
            dr[rep] = MFMA(a, *(const bf16x8*)(br+so), dr[rep]);
            dz[rep] = MFMA(a, *(const bf16x8*)(bz+so), dz[rep]);
            if (ks<4) dn[rep]  = MFMA(a, *(const bf16x8*)(bn+so), dn[rep]);
            else      dhn[rep] = MFMA(a, *(const bf16x8*)(bn+so), dhn[rep]);
          }
        }
      }
      __syncthreads();                     // all A_dec reads done before hdec overwrite
      #pragma unroll
      for (int rep=0; rep<2; ++rep) {
        int tj = wbase + rep*8;
        if (tj < 14) {
          int mt = tj/7, p = tj - mt*7;
          int col = p*16 + lr;
          #pragma unroll
          for (int e=0;e<4;++e) {
            float rg = sigf(dr[rep][e]);
            float zg = sigf(dz[rep][e]);
            float nn = tanhfast(fmaf(rg, dhn[rep][e], dn[rep][e]));
            float hnew = nn + zg*(hd[rep][e] - nn);
            hd[rep][e] = hnew;
            if (col < 100) {
              int row = mt*16 + lg*4 + e;
              unsigned short hb = f2bf(hnew);
              *(unsigned short*)(Adec + ((row*512 + (128+col)*2) ^ ((row&7)<<4))) = hb;
              *(unsigned short*)(Aenc + ((row*1792 + (784+col)*2) ^ ((row&7)<<4))) = hb;
            }
          }
        }
      }
    }
    __syncthreads();                       // new hdec visible for write GEMM

    // ---- canvas write GEMM: c += hdec @ Wwrite^T + bwrite ----
    {
      const char* WW = wsb + OWW;
      #pragma unroll
      for (int rep=0; rep<13; ++rep) {
        int j = w + rep*8;
        if (j < 98) {
          int mt = j/49, nt = j - mt*49;
          f32x4 c = creg[rep];
          int row = mt*16 + lr;
          int abase = row*512 + 256 + lg*16;
          int axor = (row&7)<<4;
          #pragma unroll
          for (int ks=0; ks<4; ++ks) {
            bf16x8 a = *(const bf16x8*)(Adec + ((abase + ks*64) ^ axor));
            c = MFMA(a, *(const bf16x8*)(WW + ((size_t)(ks*49+nt)*512 + l*8)*2), c);
          }
          f32x4 bw = *(const f32x4*)(wsb + OBWR + (size_t)(nt*256 + l*4)*4);
          c = c + bw;
          creg[rep] = c;
          #pragma unroll
          for (int e=0;e<4;++e) {
            float s = sigf(c[e]);
            int orow = mt*16 + lg*4 + e;
            int col = nt*16 + lr;
            if (t < 31) {
              *(unsigned short*)(Aenc + ((orow*1792 + col*2) ^ ((orow&7)<<4))) = f2bf(s);
            } else {
              out_c[(size_t)(blk*32+orow)*784 + col] = s;
            }
          }
        }
      }
    }
    __syncthreads();                       // sigc ready for next step
  }
}

extern "C" void kernel_launch(void* const* d_in, const int* in_sizes, int n_in,
                              void* d_out, int out_size, void* d_ws, size_t ws_size,
                              hipStream_t stream) {
  (void)in_sizes; (void)n_in; (void)out_size; (void)ws_size;
  const float* x      = (const float*)d_in[0];
  const float* noise  = (const float*)d_in[1];
  const float* ih_mu  = (const float*)d_in[2];
  const float* whh_mu = (const float*)d_in[3];
  const float* bih_mu = (const float*)d_in[4];
  const float* bhh_mu = (const float*)d_in[5];
  const float* ih_lv  = (const float*)d_in[6];
  const float* whh_lv = (const float*)d_in[7];
  const float* bih_lv = (const float*)d_in[8];
  const float* bhh_lv = (const float*)d_in[9];
  const float* wmu    = (const float*)d_in[10];
  const float* bmu    = (const float*)d_in[11];
  const float* wlv    = (const float*)d_in[12];
  const float* blv    = (const float*)d_in[13];
  const float* wih_dec= (const float*)d_in[14];
  const float* whh_dec= (const float*)d_in[15];
  const float* bih_dec= (const float*)d_in[16];
  const float* bhh_dec= (const float*)d_in[17];
  const float* wwrite = (const float*)d_in[18];
  const float* bwrite = (const float*)d_in[19];
  char* wsb = (char*)d_ws;
  float* out = (float*)d_out;

  hipFuncSetAttribute(reinterpret_cast<const void*>(draw_main),
                      hipFuncAttributeMaxDynamicSharedMemorySize, 90112);

  init_pack<<<5888, 256, 0, stream>>>(ih_mu, whh_mu, bih_mu, bhh_mu,
                                      ih_lv, whh_lv, bih_lv, bhh_lv,
                                      wmu, bmu, wlv, blv,
                                      wih_dec, whh_dec, bih_dec, bhh_dec,
                                      wwrite, bwrite, wsb);
  init_p2<<<512, 512, 0, stream>>>(x, wsb);
  draw_main<<<256, 512, 90112, stream>>>(noise, wsb, out);
}

// Round 3
// 7211.796 us; speedup vs baseline: 4.8935x; 1.0398x over previous
//
#include <hip/hip_runtime.h>
#include <cstdint>

typedef short bf16x8 __attribute__((ext_vector_type(8)));
typedef float f32x4 __attribute__((ext_vector_type(4)));

#define MFMA(a,b,c) __builtin_amdgcn_mfma_f32_16x16x32_bf16((a),(b),(c),0,0,0)

// ---------------- ws layout (bytes) ----------------
constexpr int FR = 512;                          // bf16 elems per fragment (64 lanes x 8)
constexpr size_t OP2   = 0;                                  // P2 f32 [512rt][42nt][64][4]
constexpr size_t SZP2  = (size_t)512*42*256*4;               // 22,020,096
constexpr size_t OWSUM = OP2 + SZP2;                         // [25ks][42nt][512] bf16
constexpr size_t SZWSUM= (size_t)25*42*FR*2;
constexpr size_t OWEAM = OWSUM + SZWSUM;                     // enc A-side weights mu [28][21][512]
constexpr size_t SZWEA = (size_t)28*21*FR*2;
constexpr size_t OWEAL = OWEAM + SZWEA;
constexpr size_t OWEBM = OWEAL + SZWEA;                      // enc h-side [4][21][512]
constexpr size_t SZWEB = (size_t)4*21*FR*2;
constexpr size_t OWEBL = OWEBM + SZWEB;
constexpr size_t OWH   = OWEBL + SZWEB;                      // heads [8][14][512]
constexpr size_t SZWH  = (size_t)8*14*FR*2;
constexpr size_t OWD   = OWH + SZWH;                         // dec [8][21][512]
constexpr size_t SZWD  = (size_t)8*21*FR*2;
constexpr size_t OWW   = OWD + SZWD;                         // write [4][49][512]
constexpr size_t SZWW  = (size_t)4*49*FR*2;
constexpr size_t OBP2  = OWW + SZWW;                         // f32 bias frags
constexpr size_t OBGHN = OBP2 + (size_t)42*256*4;
constexpr size_t OBDI  = OBGHN + (size_t)2*7*256*4;
constexpr size_t OBDHN = OBDI + (size_t)21*256*4;
constexpr size_t OBWR  = OBDHN + (size_t)7*256*4;
constexpr size_t OBH   = OBWR + (size_t)49*256*4;            // end ~25.1 MB

__device__ __forceinline__ float sigf(float x){ return 1.0f/(1.0f+__expf(-x)); }
__device__ __forceinline__ float tanhfast(float x){ return 1.0f - 2.0f/(__expf(2.0f*x)+1.0f); }
__device__ __forceinline__ float bf2f(unsigned short u){ return __uint_as_float(((unsigned int)u)<<16); }
__device__ __forceinline__ unsigned short f2bf(float f){ unsigned int x = __float_as_uint(f); return (unsigned short)((x + 0x8000u) >> 16); }

// ---------------- weight / bias fragment packing ----------------
__global__ void init_pack(
    const float* __restrict__ ihmu, const float* __restrict__ whhmu,
    const float* __restrict__ bihmu, const float* __restrict__ bhhmu,
    const float* __restrict__ ihlv, const float* __restrict__ whhlv,
    const float* __restrict__ bihlv, const float* __restrict__ bhhlv,
    const float* __restrict__ wmu, const float* __restrict__ bmu,
    const float* __restrict__ wlv, const float* __restrict__ blv,
    const float* __restrict__ ihd, const float* __restrict__ whhd,
    const float* __restrict__ bihd, const float* __restrict__ bhhd,
    const float* __restrict__ wwr, const float* __restrict__ bwr,
    char* __restrict__ wsb)
{
  int u = blockIdx.x*256 + threadIdx.x;
  if (u < 1469440) {
    int v = u; size_t off; int NT; int region;
    if      (v < 537600)            { region=0; off=OWSUM; NT=42; }
    else if ((v-=537600) < 301056)  { region=1; off=OWEAM; NT=21; }
    else if ((v-=301056) < 301056)  { region=2; off=OWEAL; NT=21; }
    else if ((v-=301056) < 43008)   { region=3; off=OWEBM; NT=21; }
    else if ((v-=43008)  < 43008)   { region=4; off=OWEBL; NT=21; }
    else if ((v-=43008)  < 57344)   { region=5; off=OWH;   NT=14; }
    else if ((v-=57344)  < 86016)   { region=6; off=OWD;   NT=21; }
    else    { v-=86016;   region=7; off=OWW;   NT=49; }
    int ks = v / (NT*512); int rem = v - ks*(NT*512);
    int nt = rem >> 9; int li = rem & 511;
    int l = li >> 3, e = li & 7;
    int k = ks*32 + ((l>>4)<<3) + e;
    int c = l & 15;
    float val = 0.f;
    if (region==0) {
      int gru = nt/21, ntg = nt%21, gate = ntg/7, j = (ntg%7)*16 + c;
      if (j<100 && k<784) { const float* IH = gru? ihlv : ihmu; int jj = gate*100+j;
        val = IH[(size_t)jj*1668 + k] + IH[(size_t)jj*1668 + 784 + k]; }
    } else if (region==1 || region==2) {
      const float* IH = (region==2)? ihlv : ihmu;
      int gate = nt/7, j = (nt%7)*16 + c;
      if (j<100) { int jj = gate*100+j;
        if (k<784)      val = -IH[(size_t)jj*1668 + 784 + k];
        else if (k<884) val =  IH[(size_t)jj*1668 + 1568 + (k-784)]; }
    } else if (region==3 || region==4) {
      const float* WHH = (region==4)? whhlv : whhmu;
      int gate = nt/7, j = (nt%7)*16 + c;
      if (j<100 && k<100) val = WHH[(gate*100+j)*100 + k];
    } else if (region==5) {
      int grp = nt/7, j = (nt%7)*16 + c;
      if (j<100) {
        if (grp==0) { if (k<100) val = wmu[j*100+k]; }
        else        { if (k>=128 && k<228) val = wlv[j*100 + (k-128)]; }
      }
    } else if (region==6) {
      int gate = nt/7, j = (nt%7)*16 + c;
      if (j<100) { int jj = gate*100+j;
        if (k<100)               val = ihd[jj*100+k];
        else if (k>=128 && k<228) val = whhd[jj*100 + (k-128)]; }
    } else {
      int n = nt*16 + c;
      if (k<100) val = wwr[n*100+k];
    }
    *(unsigned short*)(wsb + off + (size_t)v*2) = f2bf(val);
    return;
  }
  u -= 1469440;
  if (u >= 37632) return;
  float val = 0.f; size_t off; int v = u;
  if (v < 10752) { off = OBP2;
    int nt = v>>8, li = v&255, l = li>>2, c = l&15;
    int gru = nt/21, ntg = nt%21, gate = ntg/7, j = (ntg%7)*16 + c;
    if (j<100) {
      const float* BI = gru? bihlv : bihmu; const float* BH = gru? bhhlv : bhhmu;
      val = BI[gate*100+j] + ((gate<2)? BH[gate*100+j] : 0.f);
    }
  } else if ((v-=10752) < 3584) { off = OBGHN;
    int g = v/1792, r2 = v - g*1792, p = r2>>8, li = r2&255, l = li>>2, c = l&15;
    int j = p*16+c;
    if (j<100) val = (g? bhhlv : bhhmu)[200+j];
  } else if ((v-=3584) < 5376) { off = OBDI;
    int nt = v>>8, li = v&255, l = li>>2, c = l&15;
    int gate = nt/7, j = (nt%7)*16+c;
    if (j<100) val = (gate<2)? (bihd[gate*100+j]+bhhd[gate*100+j]) : bihd[200+j];
  } else if ((v-=5376) < 1792) { off = OBDHN;
    int p = v>>8, li = v&255, l = li>>2, c = l&15; int j = p*16+c;
    if (j<100) val = bhhd[200+j];
  } else if ((v-=1792) < 12544) { off = OBWR;
    int nt = v>>8, li = v&255, l = li>>2, c = l&15;
    val = bwr[nt*16+c];
  } else { v -= 12544; off = OBH;
    int nt = v>>8, li = v&255, l = li>>2, c = l&15;
    int grp = nt/7, j = (nt%7)*16+c;
    if (j<100) val = grp? blv[j] : bmu[j];
  }
  *(float*)(wsb + off + (size_t)v*4) = val;
}

// ---------------- P2 = x@(W1+W2)^T + bias, fragment-packed f32 ----------------
__global__ __launch_bounds__(512) void init_p2(const float* __restrict__ x, char* __restrict__ wsb)
{
  __shared__ char xt[16*1600];
  const int tid = threadIdx.x, l = tid&63, w = tid>>6;
  const int lr = l&15, lg = l>>4;
  const int rt = blockIdx.x;
  for (int i = tid; i < 16*800; i += 512) {
    int row = i/800, col = i - row*800;
    unsigned short hv = 0;
    if (col < 784) hv = f2bf(x[(size_t)(rt*16+row)*784 + col]);
    *(unsigned short*)(xt + ((row*1600 + col*2) ^ ((row&7)<<4))) = hv;
  }
  __syncthreads();
  const char* WS = wsb + OWSUM;
  for (int nt = w; nt < 42; nt += 8) {
    f32x4 acc = *(const f32x4*)(wsb + OBP2 + (size_t)(nt*256 + l*4)*4);
    const char* wp = WS + (size_t)(nt*512 + l*8)*2;
    #pragma unroll 5
    for (int ks = 0; ks < 25; ++ks) {
      bf16x8 a = *(const bf16x8*)(xt + ((lr*1600 + ks*64 + lg*16) ^ ((lr&7)<<4)));
      bf16x8 b = *(const bf16x8*)(wp + (size_t)ks*42*512*2);
      acc = MFMA(a,b,acc);
    }
    *(f32x4*)(wsb + OP2 + ((size_t)(rt*42+nt)*64 + l)*16) = acc;
  }
}

// ---------------- encoder GRU (GEMM + in-register update) ----------------
__device__ __forceinline__ void enc_gru(
    int g, int wbase, const char* wsb, const char* Aenc, char* Ahml,
    int l, int lr, int lg, f32x4 (&h)[2],
    const f32x4 (&p2)[2][3], const f32x4 (&ahnb)[2])
{
  const char* WA = wsb + (g? OWEAL : OWEAM);
  const char* WB = wsb + (g? OWEBL : OWEBM);
  f32x4 ar[2], az[2], an[2], ahn[2];
  #pragma unroll
  for (int rep=0; rep<2; ++rep) {
    int tj = wbase + rep*8;
    if (tj < 14) {
      int mt = tj/7, p = tj - mt*7;
      ar[rep] = p2[rep][0];
      az[rep] = p2[rep][1];
      an[rep] = p2[rep][2];
      ahn[rep] = ahnb[rep];
      const char* wr = WA + (size_t)(p*512 + l*8)*2;
      const char* wz = WA + (size_t)((p+7)*512 + l*8)*2;
      const char* wn = WA + (size_t)((p+14)*512 + l*8)*2;
      int row = mt*16 + lr;
      int abase = row*1792 + lg*16;
      int axor = (row&7)<<4;
      #pragma unroll 4
      for (int ks=0; ks<28; ++ks) {
        bf16x8 a = *(const bf16x8*)(Aenc + ((abase + ks*64) ^ axor));
        size_t so = (size_t)ks*21*512*2;
        ar[rep] = MFMA(a, *(const bf16x8*)(wr+so), ar[rep]);
        az[rep] = MFMA(a, *(const bf16x8*)(wz+so), az[rep]);
        an[rep] = MFMA(a, *(const bf16x8*)(wn+so), an[rep]);
      }
      const char* vr = WB + (size_t)(p*512 + l*8)*2;
      const char* vz = WB + (size_t)((p+7)*512 + l*8)*2;
      const char* vn = WB + (size_t)((p+14)*512 + l*8)*2;
      int hbase = row*512 + g*256 + lg*16;
      #pragma unroll
      for (int ks=0; ks<4; ++ks) {
        bf16x8 a = *(const bf16x8*)(Ahml + ((hbase + ks*64) ^ axor));
        size_t so = (size_t)ks*21*512*2;
        ar[rep]  = MFMA(a, *(const bf16x8*)(vr+so), ar[rep]);
        az[rep]  = MFMA(a, *(const bf16x8*)(vz+so), az[rep]);
        ahn[rep] = MFMA(a, *(const bf16x8*)(vn+so), ahn[rep]);
      }
    }
  }
  __syncthreads();
  #pragma unroll
  for (int rep=0; rep<2; ++rep) {
    int tj = wbase + rep*8;
    if (tj < 14) {
      int mt = tj/7, p = tj - mt*7;
      int col = p*16 + lr;
      #pragma unroll
      for (int e=0;e<4;++e) {
        float rg = sigf(ar[rep][e]);
        float zg = sigf(az[rep][e]);
        float nn = tanhfast(fmaf(rg, ahn[rep][e], an[rep][e]));
        float hnew = nn + zg*(h[rep][e] - nn);
        h[rep][e] = hnew;
        if (col < 100) {
          int row = mt*16 + lg*4 + e;
          *(unsigned short*)(Ahml + ((row*512 + (g*128+col)*2) ^ ((row&7)<<4))) = f2bf(hnew);
        }
      }
    }
  }
}

// ---------------- main persistent kernel ----------------
__global__ __launch_bounds__(512,2) void draw_main(
    const float* __restrict__ noise, const char* __restrict__ wsb, float* __restrict__ out)
{
  extern __shared__ char sm[];
  char* Aenc = sm;              // [32][1792 B] bf16: sigc(784) | hdec(100) | pad
  char* Ahml = sm + 57344;      // [32][512 B]  bf16: hmu(100) pad | hlv(100) pad
  char* Adec = sm + 73728;      // [32][512 B]  bf16: z(100) pad | hdec(100) pad

  const int tid = threadIdx.x, l = tid&63, w = tid>>6;
  const int lr = l&15, lg = l>>4;
  const int blk = blockIdx.x;

  float* out_c  = out;
  float* out_mu = out + (size_t)8192*784;
  float* out_lv = out_mu + (size_t)32*8192*100;

  for (int i = tid; i < 32*896; i += 512) {
    int row = i/896, col = i - row*896;
    unsigned short v = (col<784)? (unsigned short)0x3F00 : (unsigned short)0;
    *(unsigned short*)(Aenc + ((row*1792 + col*2) ^ ((row&7)<<4))) = v;
  }
  for (int i = tid; i < 32*256; i += 512) {
    int row = i>>8, col = i&255;
    int a = (row*512 + col*2) ^ ((row&7)<<4);
    *(unsigned short*)(Ahml + a) = 0;
    *(unsigned short*)(Adec + a) = 0;
  }

  // ---- hoist step-invariant fragments into registers ----
  f32x4 p2m[2][3], p2l[2][3], ahnm[2], ahnl[2];
  f32x4 dbr[2], dbz[2], dbn[2], dbh[2];
  #pragma unroll
  for (int rep=0; rep<2; ++rep) {
    int tjm = w + rep*8;
    if (tjm < 14) {
      int mt = tjm/7, p = tjm - mt*7;
      size_t pb = OP2 + (((size_t)(blk*2+mt)*42 + p)*64 + l)*16;
      p2m[rep][0] = *(const f32x4*)(wsb + pb);
      p2m[rep][1] = *(const f32x4*)(wsb + pb + (size_t)7*64*16);
      p2m[rep][2] = *(const f32x4*)(wsb + pb + (size_t)14*64*16);
      ahnm[rep] = *(const f32x4*)(wsb + OBGHN + (size_t)(p*256 + l*4)*4);
    }
    int tjl = ((w+2)&7) + rep*8;
    if (tjl < 14) {
      int mt = tjl/7, p = tjl - mt*7;
      size_t pb = OP2 + (((size_t)(blk*2+mt)*42 + 21 + p)*64 + l)*16;
      p2l[rep][0] = *(const f32x4*)(wsb + pb);
      p2l[rep][1] = *(const f32x4*)(wsb + pb + (size_t)7*64*16);
      p2l[rep][2] = *(const f32x4*)(wsb + pb + (size_t)14*64*16);
      ahnl[rep] = *(const f32x4*)(wsb + OBGHN + (size_t)((7+p)*256 + l*4)*4);
    }
    int tjd = ((w+4)&7) + rep*8;
    if (tjd < 14) {
      int p = tjd % 7;
      dbr[rep] = *(const f32x4*)(wsb + OBDI  + (size_t)(p*256 + l*4)*4);
      dbz[rep] = *(const f32x4*)(wsb + OBDI  + (size_t)((p+7)*256 + l*4)*4);
      dbn[rep] = *(const f32x4*)(wsb + OBDI  + (size_t)((p+14)*256 + l*4)*4);
      dbh[rep] = *(const f32x4*)(wsb + OBDHN + (size_t)(p*256 + l*4)*4);
    }
  }

  const f32x4 z4 = {0.f,0.f,0.f,0.f};
  f32x4 creg[13];
  #pragma unroll
  for (int q=0;q<13;++q) creg[q] = z4;
  f32x4 hm[2], hl[2], hd[2];
  #pragma unroll
  for (int q=0;q<2;++q){ hm[q]=z4; hl[q]=z4; hd[q]=z4; }
  __syncthreads();

  for (int t = 0; t < 32; ++t) {
    // ---- encoder GRUs ----
    enc_gru(0, w,        wsb, Aenc, Ahml, l, lr, lg, hm, p2m, ahnm);
    enc_gru(1, (w+2)&7,  wsb, Aenc, Ahml, l, lr, lg, hl, p2l, ahnl);
    __syncthreads();                       // A_hml complete for heads

    // ---- heads + reparameterize ----
    {
      const char* WH = wsb + OWH;
      f32x4 am[2], al[2];
      float noz[2][4];
      // prefetch noise early (nt: bypass-friendly, hides HBM latency under MFMAs)
      #pragma unroll
      for (int rep=0; rep<2; ++rep) {
        int j = w + rep*8;
        if (j < 14) {
          int mt = j/7, p = j - mt*7;
          int col = p*16 + lr;
          if (col < 100) {
            #pragma unroll
            for (int e=0;e<4;++e) {
              int row = mt*16 + lg*4 + e;
              size_t oidx = (size_t)t*819200 + (size_t)(blk*32+row)*100 + col;
              noz[rep][e] = __builtin_nontemporal_load(noise + oidx);
            }
          }
        }
      }
      #pragma unroll
      for (int rep=0; rep<2; ++rep) {
        int j = w + rep*8;
        if (j < 14) {
          int mt = j/7, p = j - mt*7;
          am[rep] = *(const f32x4*)(wsb + OBH + (size_t)(p*256 + l*4)*4);
          al[rep] = *(const f32x4*)(wsb + OBH + (size_t)((7+p)*256 + l*4)*4);
          int row = mt*16 + lr;
          int hbase = row*512 + lg*16;
          int axor = (row&7)<<4;
          #pragma unroll
          for (int ks=0; ks<4; ++ks) {
            bf16x8 a0 = *(const bf16x8*)(Ahml + ((hbase + ks*64) ^ axor));
            bf16x8 a1 = *(const bf16x8*)(Ahml + ((hbase + 256 + ks*64) ^ axor));
            am[rep] = MFMA(a0, *(const bf16x8*)(WH + ((size_t)(ks*14+p)*512 + l*8)*2), am[rep]);
            al[rep] = MFMA(a1, *(const bf16x8*)(WH + ((size_t)((ks+4)*14+7+p)*512 + l*8)*2), al[rep]);
          }
        }
      }
      #pragma unroll
      for (int rep=0; rep<2; ++rep) {
        int j = w + rep*8;
        if (j < 14) {
          int mt = j/7, p = j - mt*7;
          int col = p*16 + lr;
          if (col < 100) {
            #pragma unroll
            for (int e=0;e<4;++e) {
              int row = mt*16 + lg*4 + e;
              float m  = fmaxf(am[rep][e], 0.f);
              float lv = fmaxf(al[rep][e], 0.f);
              size_t oidx = (size_t)t*819200 + (size_t)(blk*32+row)*100 + col;
              __builtin_nontemporal_store(m,  out_mu + oidx);
              __builtin_nontemporal_store(lv, out_lv + oidx);
              float zz = fmaf(noz[rep][e], __expf(0.5f*lv), m);
              *(unsigned short*)(Adec + ((row*512 + col*2) ^ ((row&7)<<4))) = f2bf(zz);
            }
          }
        }
      }
    }
    __syncthreads();                       // A_dec z-region ready

    // ---- decoder GRU ----
    {
      const char* WD = wsb + OWD;
      int wbase = (w+4)&7;
      f32x4 dr[2], dz[2], dn[2], dhn[2];
      #pragma unroll
      for (int rep=0; rep<2; ++rep) {
        int tj = wbase + rep*8;
        if (tj < 14) {
          int mt = tj/7, p = tj - mt*7;
          dr[rep]  = dbr[rep];
          dz[rep]  = dbz[rep];
          dn[rep]  = dbn[rep];
          dhn[rep] = dbh[rep];
          const char* br = WD + (size_t)(p*512 + l*8)*2;
          const char* bz = WD + (size_t)((p+7)*512 + l*8)*2;
          const char* bn = WD + (size_t)((p+14)*512 + l*8)*2;
          int row = mt*16 + lr;
          int abase = row*512 + lg*16;
          int axor = (row&7)<<4;
          #pragma unroll
          for (int ks=0; ks<8; ++ks) {
            bf16x8 a = *(const bf16x8*)(Adec + ((abase + ks*64) ^ axor));
            size_t so = (size_t)ks*21*512*2;
            dr[rep] = MFMA(a, *(const bf16x8*)(br+so), dr[rep]);
            dz[rep] = MFMA(a, *(const bf16x8*)(bz+so), dz[rep]);
            if (ks<4) dn[rep]  = MFMA(a, *(const bf16x8*)(bn+so), dn[rep]);
            else      dhn[rep] = MFMA(a, *(const bf16x8*)(bn+so), dhn[rep]);
          }
        }
      }
      __syncthreads();                     // all A_dec reads done before hdec overwrite
      #pragma unroll
      for (int rep=0; rep<2; ++rep) {
        int tj = wbase + rep*8;
        if (tj < 14) {
          int mt = tj/7, p = tj - mt*7;
          int col = p*16 + lr;
          #pragma unroll
          for (int e=0;e<4;++e) {
            float rg = sigf(dr[rep][e]);
            float zg = sigf(dz[rep][e]);
            float nn = tanhfast(fmaf(rg, dhn[rep][e], dn[rep][e]));
            float hnew = nn + zg*(hd[rep][e] - nn);
            hd[rep][e] = hnew;
            if (col < 100) {
              int row = mt*16 + lg*4 + e;
              unsigned short hb = f2bf(hnew);
              *(unsigned short*)(Adec + ((row*512 + (128+col)*2) ^ ((row&7)<<4))) = hb;
              *(unsigned short*)(Aenc + ((row*1792 + (784+col)*2) ^ ((row&7)<<4))) = hb;
            }
          }
        }
      }
    }
    __syncthreads();                       // new hdec visible for write GEMM

    // ---- canvas write GEMM: c += hdec @ Wwrite^T + bwrite ----
    {
      const char* WW = wsb + OWW;
      #pragma unroll
      for (int rep=0; rep<13; ++rep) {
        int j = w + rep*8;
        if (j < 98) {
          int mt = j/49, nt = j - mt*49;
          f32x4 c = creg[rep];
          int row = mt*16 + lr;
          int abase = row*512 + 256 + lg*16;
          int axor = (row&7)<<4;
          #pragma unroll
          for (int ks=0; ks<4; ++ks) {
            bf16x8 a = *(const bf16x8*)(Adec + ((abase + ks*64) ^ axor));
            c = MFMA(a, *(const bf16x8*)(WW + ((size_t)(ks*49+nt)*512 + l*8)*2), c);
          }
          f32x4 bw = *(const f32x4*)(wsb + OBWR + (size_t)(nt*256 + l*4)*4);
          c = c + bw;
          creg[rep] = c;
          #pragma unroll
          for (int e=0;e<4;++e) {
            float s = sigf(c[e]);
            int orow = mt*16 + lg*4 + e;
            int col = nt*16 + lr;
            if (t < 31) {
              *(unsigned short*)(Aenc + ((orow*1792 + col*2) ^ ((orow&7)<<4))) = f2bf(s);
            } else {
              __builtin_nontemporal_store(s, out_c + (size_t)(blk*32+orow)*784 + col);
            }
          }
        }
      }
    }
    __syncthreads();                       // sigc ready for next step
  }
}

extern "C" void kernel_launch(void* const* d_in, const int* in_sizes, int n_in,
                              void* d_out, int out_size, void* d_ws, size_t ws_size,
                              hipStream_t stream) {
  (void)in_sizes; (void)n_in; (void)out_size; (void)ws_size;
  const float* x      = (const float*)d_in[0];
  const float* noise  = (const float*)d_in[1];
  const float* ih_mu  = (const float*)d_in[2];
  const float* whh_mu = (const float*)d_in[3];
  const float* bih_mu = (const float*)d_in[4];
  const float* bhh_mu = (const float*)d_in[5];
  const float* ih_lv  = (const float*)d_in[6];
  const float* whh_lv = (const float*)d_in[7];
  const float* bih_lv = (const float*)d_in[8];
  const float* bhh_lv = (const float*)d_in[9];
  const float* wmu    = (const float*)d_in[10];
  const float* bmu    = (const float*)d_in[11];
  const float* wlv    = (const float*)d_in[12];
  const float* blv    = (const float*)d_in[13];
  const float* wih_dec= (const float*)d_in[14];
  const float* whh_dec= (const float*)d_in[15];
  const float* bih_dec= (const float*)d_in[16];
  const float* bhh_dec= (const float*)d_in[17];
  const float* wwrite = (const float*)d_in[18];
  const float* bwrite = (const float*)d_in[19];
  char* wsb = (char*)d_ws;
  float* out = (float*)d_out;

  hipFuncSetAttribute(reinterpret_cast<const void*>(draw_main),
                      hipFuncAttributeMaxDynamicSharedMemorySize, 90112);

  init_pack<<<5888, 256, 0, stream>>>(ih_mu, whh_mu, bih_mu, bhh_mu,
                                      ih_lv, whh_lv, bih_lv, bhh_lv,
                                      wmu, bmu, wlv, blv,
                                      wih_dec, whh_dec, bih_dec, bhh_dec,
                                      wwrite, bwrite, wsb);
  init_p2<<<512, 512, 0, stream>>>(x, wsb);
  draw_main<<<256, 512, 90112, stream>>>(noise, wsb, out);
}

// Round 5
// 4697.744 us; speedup vs baseline: 7.5124x; 1.5352x over previous
//
#include <hip/hip_runtime.h>
#include <cstdint>

typedef short bf16x8 __attribute__((ext_vector_type(8)));
typedef float f32x4 __attribute__((ext_vector_type(4)));

#define MFMA(a,b,c) __builtin_amdgcn_mfma_f32_16x16x32_bf16((a),(b),(c),0,0,0)

// ---------------- ws layout (bytes) ----------------
constexpr int FR = 512;                          // bf16 elems per fragment (64 lanes x 8)
constexpr size_t OP2   = 0;                                  // P2 f32 [512rt][42nt][64][4]
constexpr size_t SZP2  = (size_t)512*42*256*4;               // 22,020,096
constexpr size_t OWSUM = OP2 + SZP2;                         // [25ks][42nt][512] bf16
constexpr size_t SZWSUM= (size_t)25*42*FR*2;
constexpr size_t OWEAM = OWSUM + SZWSUM;                     // enc A-side weights mu [28][21][512]
constexpr size_t SZWEA = (size_t)28*21*FR*2;
constexpr size_t OWEAL = OWEAM + SZWEA;
constexpr size_t OWEBM = OWEAL + SZWEA;                      // enc h-side [4][21][512]
constexpr size_t SZWEB = (size_t)4*21*FR*2;
constexpr size_t OWEBL = OWEBM + SZWEB;
constexpr size_t OWH   = OWEBL + SZWEB;                      // heads [8][14][512]
constexpr size_t SZWH  = (size_t)8*14*FR*2;
constexpr size_t OWD   = OWH + SZWH;                         // dec [8][21][512]
constexpr size_t SZWD  = (size_t)8*21*FR*2;
constexpr size_t OWW   = OWD + SZWD;                         // write [4][49][512]
constexpr size_t SZWW  = (size_t)4*49*FR*2;
constexpr size_t OBP2  = OWW + SZWW;                         // f32 bias frags
constexpr size_t OBGHN = OBP2 + (size_t)42*256*4;
constexpr size_t OBDI  = OBGHN + (size_t)2*7*256*4;
constexpr size_t OBDHN = OBDI + (size_t)21*256*4;
constexpr size_t OBWR  = OBDHN + (size_t)7*256*4;
constexpr size_t OBH   = OBWR + (size_t)49*256*4;            // end ~25.1 MB

__device__ __forceinline__ float sigf(float x){ return 1.0f/(1.0f+__expf(-x)); }
__device__ __forceinline__ float tanhfast(float x){ return 1.0f - 2.0f/(__expf(2.0f*x)+1.0f); }
__device__ __forceinline__ float bf2f(unsigned short u){ return __uint_as_float(((unsigned int)u)<<16); }
__device__ __forceinline__ unsigned short f2bf(float f){ unsigned int x = __float_as_uint(f); return (unsigned short)((x + 0x8000u) >> 16); }

// ---------------- weight / bias fragment packing ----------------
__global__ void init_pack(
    const float* __restrict__ ihmu, const float* __restrict__ whhmu,
    const float* __restrict__ bihmu, const float* __restrict__ bhhmu,
    const float* __restrict__ ihlv, const float* __restrict__ whhlv,
    const float* __restrict__ bihlv, const float* __restrict__ bhhlv,
    const float* __restrict__ wmu, const float* __restrict__ bmu,
    const float* __restrict__ wlv, const float* __restrict__ blv,
    const float* __restrict__ ihd, const float* __restrict__ whhd,
    const float* __restrict__ bihd, const float* __restrict__ bhhd,
    const float* __restrict__ wwr, const float* __restrict__ bwr,
    char* __restrict__ wsb)
{
  int u = blockIdx.x*256 + threadIdx.x;
  if (u < 1469440) {
    int v = u; size_t off; int NT; int region;
    if      (v < 537600)            { region=0; off=OWSUM; NT=42; }
    else if ((v-=537600) < 301056)  { region=1; off=OWEAM; NT=21; }
    else if ((v-=301056) < 301056)  { region=2; off=OWEAL; NT=21; }
    else if ((v-=301056) < 43008)   { region=3; off=OWEBM; NT=21; }
    else if ((v-=43008)  < 43008)   { region=4; off=OWEBL; NT=21; }
    else if ((v-=43008)  < 57344)   { region=5; off=OWH;   NT=14; }
    else if ((v-=57344)  < 86016)   { region=6; off=OWD;   NT=21; }
    else    { v-=86016;   region=7; off=OWW;   NT=49; }
    int ks = v / (NT*512); int rem = v - ks*(NT*512);
    int nt = rem >> 9; int li = rem & 511;
    int l = li >> 3, e = li & 7;
    int k = ks*32 + ((l>>4)<<3) + e;
    int c = l & 15;
    float val = 0.f;
    if (region==0) {
      int gru = nt/21, ntg = nt%21, gate = ntg/7, j = (ntg%7)*16 + c;
      if (j<100 && k<784) { const float* IH = gru? ihlv : ihmu; int jj = gate*100+j;
        val = IH[(size_t)jj*1668 + k] + IH[(size_t)jj*1668 + 784 + k]; }
    } else if (region==1 || region==2) {
      const float* IH = (region==2)? ihlv : ihmu;
      int gate = nt/7, j = (nt%7)*16 + c;
      if (j<100) { int jj = gate*100+j;
        if (k<784)      val = -IH[(size_t)jj*1668 + 784 + k];
        else if (k<884) val =  IH[(size_t)jj*1668 + 1568 + (k-784)]; }
    } else if (region==3 || region==4) {
      const float* WHH = (region==4)? whhlv : whhmu;
      int gate = nt/7, j = (nt%7)*16 + c;
      if (j<100 && k<100) val = WHH[(gate*100+j)*100 + k];
    } else if (region==5) {
      int grp = nt/7, j = (nt%7)*16 + c;
      if (j<100) {
        if (grp==0) { if (k<100) val = wmu[j*100+k]; }
        else        { if (k>=128 && k<228) val = wlv[j*100 + (k-128)]; }
      }
    } else if (region==6) {
      int gate = nt/7, j = (nt%7)*16 + c;
      if (j<100) { int jj = gate*100+j;
        if (k<100)               val = ihd[jj*100+k];
        else if (k>=128 && k<228) val = whhd[jj*100 + (k-128)]; }
    } else {
      int n = nt*16 + c;
      if (k<100) val = wwr[n*100+k];
    }
    *(unsigned short*)(wsb + off + (size_t)v*2) = f2bf(val);
    return;
  }
  u -= 1469440;
  if (u >= 37632) return;
  float val = 0.f; size_t off; int v = u;
  if (v < 10752) { off = OBP2;
    int nt = v>>8, li = v&255, l = li>>2, c = l&15;
    int gru = nt/21, ntg = nt%21, gate = ntg/7, j = (ntg%7)*16 + c;
    if (j<100) {
      const float* BI = gru? bihlv : bihmu; const float* BH = gru? bhhlv : bhhmu;
      val = BI[gate*100+j] + ((gate<2)? BH[gate*100+j] : 0.f);
    }
  } else if ((v-=10752) < 3584) { off = OBGHN;
    int g = v/1792, r2 = v - g*1792, p = r2>>8, li = r2&255, l = li>>2, c = l&15;
    int j = p*16+c;
    if (j<100) val = (g? bhhlv : bhhmu)[200+j];
  } else if ((v-=3584) < 5376) { off = OBDI;
    int nt = v>>8, li = v&255, l = li>>2, c = l&15;
    int gate = nt/7, j = (nt%7)*16+c;
    if (j<100) val = (gate<2)? (bihd[gate*100+j]+bhhd[gate*100+j]) : bihd[200+j];
  } else if ((v-=5376) < 1792) { off = OBDHN;
    int p = v>>8, li = v&255, l = li>>2, c = l&15; int j = p*16+c;
    if (j<100) val = bhhd[200+j];
  } else if ((v-=1792) < 12544) { off = OBWR;
    int nt = v>>8, li = v&255, l = li>>2, c = l&15;
    val = bwr[nt*16+c];
  } else { v -= 12544; off = OBH;
    int nt = v>>8, li = v&255, l = li>>2, c = l&15;
    int grp = nt/7, j = (nt%7)*16+c;
    if (j<100) val = grp? blv[j] : bmu[j];
  }
  *(float*)(wsb + off + (size_t)v*4) = val;
}

// ---------------- P2 = x@(W1+W2)^T + bias, fragment-packed f32 ----------------
__global__ __launch_bounds__(512) void init_p2(const float* __restrict__ x, char* __restrict__ wsb)
{
  __shared__ char xt[16*1600];
  const int tid = threadIdx.x, l = tid&63, w = tid>>6;
  const int lr = l&15, lg = l>>4;
  const int rt = blockIdx.x;
  for (int i = tid; i < 16*800; i += 512) {
    int row = i/800, col = i - row*800;
    unsigned short hv = 0;
    if (col < 784) hv = f2bf(x[(size_t)(rt*16+row)*784 + col]);
    *(unsigned short*)(xt + ((row*1600 + col*2) ^ ((row&7)<<4))) = hv;
  }
  __syncthreads();
  const char* WS = wsb + OWSUM;
  for (int nt = w; nt < 42; nt += 8) {
    f32x4 acc = *(const f32x4*)(wsb + OBP2 + (size_t)(nt*256 + l*4)*4);
    const char* wp = WS + (size_t)(nt*512 + l*8)*2;
    #pragma unroll 5
    for (int ks = 0; ks < 25; ++ks) {
      bf16x8 a = *(const bf16x8*)(xt + ((lr*1600 + ks*64 + lg*16) ^ ((lr&7)<<4)));
      bf16x8 b = *(const bf16x8*)(wp + (size_t)ks*42*512*2);
      acc = MFMA(a,b,acc);
    }
    *(f32x4*)(wsb + OP2 + ((size_t)(rt*42+nt)*64 + l)*16) = acc;
  }
}

// ---------------- encoder GRU (GEMM + in-register update), 16 rows ----------------
__device__ __forceinline__ void enc_gru(
    int g, int p, const char* wsb, const char* Aenc, char* Ahml,
    int l, int lr, int lg, f32x4 &h, const f32x4 (&p2)[3], const f32x4 &ahnb)
{
  const char* WA = wsb + (g? OWEAL : OWEAM);
  const char* WB = wsb + (g? OWEBL : OWEBM);
  f32x4 ar, az, an, ahn;
  const bool act = (p < 7);
  if (act) {
    ar = p2[0]; az = p2[1]; an = p2[2]; ahn = ahnb;
    const char* wr = WA + (size_t)(p*512 + l*8)*2;
    const char* wz = WA + (size_t)((p+7)*512 + l*8)*2;
    const char* wn = WA + (size_t)((p+14)*512 + l*8)*2;
    int abase = lr*1792 + lg*16;
    int axor = (lr&7)<<4;
    #pragma unroll 4
    for (int ks=0; ks<28; ++ks) {
      bf16x8 a = *(const bf16x8*)(Aenc + ((abase + ks*64) ^ axor));
      size_t so = (size_t)ks*21*512*2;
      ar = MFMA(a, *(const bf16x8*)(wr+so), ar);
      az = MFMA(a, *(const bf16x8*)(wz+so), az);
      an = MFMA(a, *(const bf16x8*)(wn+so), an);
    }
    const char* vr = WB + (size_t)(p*512 + l*8)*2;
    const char* vz = WB + (size_t)((p+7)*512 + l*8)*2;
    const char* vn = WB + (size_t)((p+14)*512 + l*8)*2;
    int hbase = lr*512 + g*256 + lg*16;
    #pragma unroll
    for (int ks=0; ks<4; ++ks) {
      bf16x8 a = *(const bf16x8*)(Ahml + ((hbase + ks*64) ^ axor));
      size_t so = (size_t)ks*21*512*2;
      ar  = MFMA(a, *(const bf16x8*)(vr+so), ar);
      az  = MFMA(a, *(const bf16x8*)(vz+so), az);
      ahn = MFMA(a, *(const bf16x8*)(vn+so), ahn);
    }
  }
  __syncthreads();
  if (act) {
    int col = p*16 + lr;
    #pragma unroll
    for (int e=0;e<4;++e) {
      float rg = sigf(ar[e]);
      float zg = sigf(az[e]);
      float nn = tanhfast(fmaf(rg, ahn[e], an[e]));
      float hnew = nn + zg*(h[e] - nn);
      h[e] = hnew;
      if (col < 100) {
        int row = lg*4 + e;
        *(unsigned short*)(Ahml + ((row*512 + (g*128+col)*2) ^ ((row&7)<<4))) = f2bf(hnew);
      }
    }
  }
}

// ---------------- main persistent kernel: 16 rows/block, 512 blocks ----------------
__global__ __launch_bounds__(512,4) void draw_main(
    const float* __restrict__ noise, const char* __restrict__ wsb, float* __restrict__ out)
{
  extern __shared__ char sm[];
  char* Aenc = sm;               // [16][1792 B] bf16: sigc(784) | hdec(100) | pad
  char* Ahml = sm + 28672;       // [16][512 B]  bf16: hmu(100) pad | hlv(100) pad
  char* Adec = sm + 36864;       // [16][512 B]  bf16: z(100) pad | hdec(100) pad
  float* muv = (float*)(sm + 45056);  // [16][100] mu | [16][100] lv (f32, row-major dense)

  const int tid = threadIdx.x, l = tid&63, w = tid>>6;
  const int lr = l&15, lg = l>>4;
  const int blk = blockIdx.x;

  float* out_c  = out;
  float* out_mu = out + (size_t)8192*784;
  float* out_lv = out_mu + (size_t)32*8192*100;

  for (int i = tid; i < 16*896; i += 512) {
    int row = i/896, col = i - row*896;
    unsigned short v = (col<784)? (unsigned short)0x3F00 : (unsigned short)0;
    *(unsigned short*)(Aenc + ((row*1792 + col*2) ^ ((row&7)<<4))) = v;
  }
  for (int i = tid; i < 16*256; i += 512) {
    int row = i>>8, col = i&255;
    int a = (row*512 + col*2) ^ ((row&7)<<4);
    *(unsigned short*)(Ahml + a) = 0;
    *(unsigned short*)(Adec + a) = 0;
  }

  // ---- hoist step-invariant fragments into registers ----
  const f32x4 z4 = {0.f,0.f,0.f,0.f};
  f32x4 p2m[3] = {z4,z4,z4}, p2l[3] = {z4,z4,z4}, ahnm = z4, ahnl = z4;
  {
    int pm = w;
    if (pm < 7) {
      size_t pb = OP2 + (((size_t)blk*42 + pm)*64 + l)*16;
      p2m[0] = *(const f32x4*)(wsb + pb);
      p2m[1] = *(const f32x4*)(wsb + pb + (size_t)7*64*16);
      p2m[2] = *(const f32x4*)(wsb + pb + (size_t)14*64*16);
      ahnm = *(const f32x4*)(wsb + OBGHN + (size_t)(pm*256 + l*4)*4);
    }
    int pl = (w+2)&7;
    if (pl < 7) {
      size_t pb = OP2 + (((size_t)blk*42 + 21 + pl)*64 + l)*16;
      p2l[0] = *(const f32x4*)(wsb + pb);
      p2l[1] = *(const f32x4*)(wsb + pb + (size_t)7*64*16);
      p2l[2] = *(const f32x4*)(wsb + pb + (size_t)14*64*16);
      ahnl = *(const f32x4*)(wsb + OBGHN + (size_t)((7+pl)*256 + l*4)*4);
    }
  }

  f32x4 creg[7];
  #pragma unroll
  for (int q=0;q<7;++q) creg[q] = z4;
  f32x4 hm = z4, hl = z4, hd = z4;
  __syncthreads();

  for (int t = 0; t < 32; ++t) {
    // ---- encoder GRUs ----
    enc_gru(0, w,       wsb, Aenc, Ahml, l, lr, lg, hm, p2m, ahnm);
    enc_gru(1, (w+2)&7, wsb, Aenc, Ahml, l, lr, lg, hl, p2l, ahnl);
    __syncthreads();                       // A_hml complete for heads

    // ---- heads + reparameterize (stage mu/lv/z in LDS) ----
    {
      const char* WH = wsb + OWH;
      if (w < 7) {
        int p = w;
        int col = p*16 + lr;
        float noz[4];
        if (col < 100) {
          #pragma unroll
          for (int e=0;e<4;++e) {
            int row = lg*4 + e;
            size_t oidx = (size_t)t*819200 + (size_t)(blk*16+row)*100 + col;
            noz[e] = __builtin_nontemporal_load(noise + oidx);
          }
        }
        f32x4 am = *(const f32x4*)(wsb + OBH + (size_t)(p*256 + l*4)*4);
        f32x4 al = *(const f32x4*)(wsb + OBH + (size_t)((7+p)*256 + l*4)*4);
        int hbase = lr*512 + lg*16;
        int axor = (lr&7)<<4;
        #pragma unroll
        for (int ks=0; ks<4; ++ks) {
          bf16x8 a0 = *(const bf16x8*)(Ahml + ((hbase + ks*64) ^ axor));
          bf16x8 a1 = *(const bf16x8*)(Ahml + ((hbase + 256 + ks*64) ^ axor));
          am = MFMA(a0, *(const bf16x8*)(WH + ((size_t)(ks*14+p)*512 + l*8)*2), am);
          al = MFMA(a1, *(const bf16x8*)(WH + ((size_t)((ks+4)*14+7+p)*512 + l*8)*2), al);
        }
        if (col < 100) {
          #pragma unroll
          for (int e=0;e<4;++e) {
            int row = lg*4 + e;
            float m  = fmaxf(am[e], 0.f);
            float lv = fmaxf(al[e], 0.f);
            muv[row*100 + col]        = m;
            muv[1600 + row*100 + col] = lv;
            float zz = fmaf(noz[e], __expf(0.5f*lv), m);
            *(unsigned short*)(Adec + ((row*512 + col*2) ^ ((row&7)<<4))) = f2bf(zz);
          }
        }
      }
    }
    __syncthreads();                       // muv + A_dec z-region ready

    // ---- coalesced NT store of mu/lv (dense 6400B, 64B-aligned regions) ----
    {
      size_t base = (size_t)t*819200 + (size_t)blk*1600;
      for (int i = tid; i < 800; i += 512) {
        f32x4 v = ((const f32x4*)muv)[i];
        if (i < 400) __builtin_nontemporal_store(v, (f32x4*)(out_mu + base) + i);
        else         __builtin_nontemporal_store(v, (f32x4*)(out_lv + base) + (i-400));
      }
    }

    // ---- decoder GRU ----
    {
      const char* WD = wsb + OWD;
      int p = (w+4)&7;
      f32x4 dr, dz, dn, dhn;
      if (p < 7) {
        dr  = *(const f32x4*)(wsb + OBDI  + (size_t)(p*256 + l*4)*4);
        dz  = *(const f32x4*)(wsb + OBDI  + (size_t)((p+7)*256 + l*4)*4);
        dn  = *(const f32x4*)(wsb + OBDI  + (size_t)((p+14)*256 + l*4)*4);
        dhn = *(const f32x4*)(wsb + OBDHN + (size_t)(p*256 + l*4)*4);
        const char* br = WD + (size_t)(p*512 + l*8)*2;
        const char* bz = WD + (size_t)((p+7)*512 + l*8)*2;
        const char* bn = WD + (size_t)((p+14)*512 + l*8)*2;
        int abase = lr*512 + lg*16;
        int axor = (lr&7)<<4;
        #pragma unroll
        for (int ks=0; ks<8; ++ks) {
          bf16x8 a = *(const bf16x8*)(Adec + ((abase + ks*64) ^ axor));
          size_t so = (size_t)ks*21*512*2;
          dr = MFMA(a, *(const bf16x8*)(br+so), dr);
          dz = MFMA(a, *(const bf16x8*)(bz+so), dz);
          if (ks<4) dn  = MFMA(a, *(const bf16x8*)(bn+so), dn);
          else      dhn = MFMA(a, *(const bf16x8*)(bn+so), dhn);
        }
      }
      __syncthreads();                     // all A_dec reads done before hdec overwrite
      if (p < 7) {
        int col = p*16 + lr;
        #pragma unroll
        for (int e=0;e<4;++e) {
          float rg = sigf(dr[e]);
          float zg = sigf(dz[e]);
          float nn = tanhfast(fmaf(rg, dhn[e], dn[e]));
          float hnew = nn + zg*(hd[e] - nn);
          hd[e] = hnew;
          if (col < 100) {
            int row = lg*4 + e;
            unsigned short hb = f2bf(hnew);
            *(unsigned short*)(Adec + ((row*512 + (128+col)*2) ^ ((row&7)<<4))) = hb;
            *(unsigned short*)(Aenc + ((row*1792 + (784+col)*2) ^ ((row&7)<<4))) = hb;
          }
        }
      }
    }
    __syncthreads();                       // new hdec visible for write GEMM

    // ---- canvas write GEMM: c += hdec @ Wwrite^T + bwrite ----
    {
      const char* WW = wsb + OWW;
      #pragma unroll
      for (int rep=0; rep<7; ++rep) {
        int nt = w + rep*8;
        if (nt < 49) {
          f32x4 c = creg[rep];
          int abase = lr*512 + 256 + lg*16;
          int axor = (lr&7)<<4;
          #pragma unroll
          for (int ks=0; ks<4; ++ks) {
            bf16x8 a = *(const bf16x8*)(Adec + ((abase + ks*64) ^ axor));
            c = MFMA(a, *(const bf16x8*)(WW + ((size_t)(ks*49+nt)*512 + l*8)*2), c);
          }
          f32x4 bw = *(const f32x4*)(wsb + OBWR + (size_t)(nt*256 + l*4)*4);
          c = c + bw;
          creg[rep] = c;
          #pragma unroll
          for (int e=0;e<4;++e) {
            float s = sigf(c[e]);
            int orow = lg*4 + e;
            int col = nt*16 + lr;
            if (t < 31) {
              *(unsigned short*)(Aenc + ((orow*1792 + col*2) ^ ((orow&7)<<4))) = f2bf(s);
            } else {
              __builtin_nontemporal_store(s, out_c + (size_t)(blk*16+orow)*784 + col);
            }
          }
        }
      }
    }
    __syncthreads();                       // sigc ready for next step
  }
}

extern "C" void kernel_launch(void* const* d_in, const int* in_sizes, int n_in,
                              void* d_out, int out_size, void* d_ws, size_t ws_size,
                              hipStream_t stream) {
  (void)in_sizes; (void)n_in; (void)out_size; (void)ws_size;
  const float* x      = (const float*)d_in[0];
  const float* noise  = (const float*)d_in[1];
  const float* ih_mu  = (const float*)d_in[2];
  const float* whh_mu = (const float*)d_in[3];
  const float* bih_mu = (const float*)d_in[4];
  const float* bhh_mu = (const float*)d_in[5];
  const float* ih_lv  = (const float*)d_in[6];
  const float* whh_lv = (const float*)d_in[7];
  const float* bih_lv = (const float*)d_in[8];
  const float* bhh_lv = (const float*)d_in[9];
  const float* wmu    = (const float*)d_in[10];
  const float* bmu    = (const float*)d_in[11];
  const float* wlv    = (const float*)d_in[12];
  const float* blv    = (const float*)d_in[13];
  const float* wih_dec= (const float*)d_in[14];
  const float* whh_dec= (const float*)d_in[15];
  const float* bih_dec= (const float*)d_in[16];
  const float* bhh_dec= (const float*)d_in[17];
  const float* wwrite = (const float*)d_in[18];
  const float* bwrite = (const float*)d_in[19];
  char* wsb = (char*)d_ws;
  float* out = (float*)d_out;

  hipFuncSetAttribute(reinterpret_cast<const void*>(draw_main),
                      hipFuncAttributeMaxDynamicSharedMemorySize, 57856);

  init_pack<<<5888, 256, 0, stream>>>(ih_mu, whh_mu, bih_mu, bhh_mu,
                                      ih_lv, whh_lv, bih_lv, bhh_lv,
                                      wmu, bmu, wlv, blv,
                                      wih_dec, whh_dec, bih_dec, bhh_dec,
                                      wwrite, bwrite, wsb);
  init_p2<<<512, 512, 0, stream>>>(x, wsb);
  draw_main<<<512, 512, 57856, stream>>>(noise, wsb, out);
}